// Round 14
// baseline (860.289 us; speedup 1.0000x reference)
//
#include <hip/hip_runtime.h>
#include <hip/hip_bf16.h>
#include <math.h>

#define NN 20000
#define NE 320000
#define H 128
#define NH (NN * H)

typedef short bf16x8 __attribute__((ext_vector_type(8)));
typedef float f32x4 __attribute__((ext_vector_type(4)));
typedef unsigned short u16x8 __attribute__((ext_vector_type(8)));

__device__ __forceinline__ float lrelu(float x) { return x > 0.f ? x : 0.01f * x; }
__device__ __forceinline__ float eluf(float x)  { return x > 0.f ? x : expm1f(x); }
__device__ __forceinline__ float sigf(float x)  { return 1.f / (1.f + __expf(-x)); }
__device__ __forceinline__ unsigned short f2b(float x) {
    __hip_bfloat16 h = __float2bfloat16(x);
    return *reinterpret_cast<unsigned short*>(&h);
}
__device__ __forceinline__ float b2f(unsigned short u) {
    __hip_bfloat16 h = *reinterpret_cast<__hip_bfloat16*>(&u);
    return __bfloat162float(h);
}
#define BN_S 0.99999500003749973f  /* 1/sqrt(1+1e-5) */

// ---------------- weight pre-pack into MFMA B-fragment order --------------
struct PackPtrs { const float* w[13]; };
__global__ __launch_bounds__(256) void k_pack(PackPtrs p, unsigned short* __restrict__ dst) {
    int gid = blockIdx.x * 256 + threadIdx.x;   // 13 * 2048 threads
    int m = gid >> 11;
    int r = gid & 2047;
    int t = r >> 8, kk = (r >> 6) & 3, lane = r & 63;
    const float* W = p.w[m];
    int col = t * 16 + (lane & 15);
    int krow = kk * 32 + (lane >> 4) * 8;
    unsigned short* o = dst + (size_t)m * 16384 + (size_t)r * 8;
#pragma unroll
    for (int j = 0; j < 8; ++j) o[j] = f2b(W[(krow + j) * H + col]);
}

// ---------------- CSR build ------------------------------------------------
__global__ __launch_bounds__(256) void k_deg(const int* __restrict__ dst, int* __restrict__ deg) {
    int e = blockIdx.x * 256 + threadIdx.x;
    if (e < NE) atomicAdd(&deg[dst[e]], 1);
}

__global__ __launch_bounds__(256) void k_scan(const int* __restrict__ deg,
                                              int* __restrict__ off, int* __restrict__ cursor) {
    __shared__ int sums[256];
    const int t = threadIdx.x;
    const int per = (NN + 255) / 256;   // 79
    const int base = t * per;
    int s = 0;
    for (int i = 0; i < per; ++i) { int idx = base + i; if (idx < NN) s += deg[idx]; }
    sums[t] = s;
    __syncthreads();
    for (int d = 1; d < 256; d <<= 1) {
        int v = (t >= d) ? sums[t - d] : 0;
        __syncthreads();
        sums[t] += v;
        __syncthreads();
    }
    int run = (t == 0) ? 0 : sums[t - 1];
    for (int i = 0; i < per; ++i) {
        int idx = base + i;
        if (idx < NN) { off[idx] = run; cursor[idx] = run; run += deg[idx]; }
    }
}

// fill CSR + sequential tables in one pass
__global__ __launch_bounds__(256) void k_fill(
        const int* __restrict__ src, const int* __restrict__ dst,
        const float* __restrict__ ef,
        int* __restrict__ cursor, int* __restrict__ csr,
        int* __restrict__ srcseq, int* __restrict__ dstseq,
        float* __restrict__ efseq) {
    int e = blockIdx.x * 256 + threadIdx.x;
    if (e < NE) {
        int d = dst[e];
        int pos = atomicAdd(&cursor[d], 1);
        csr[pos]    = e;
        srcseq[pos] = src[e];
        dstseq[pos] = d;
        efseq[pos]  = ef[e];
    }
}

// ---------------- layer 0: node linears (din=2) ----------------
__global__ __launch_bounds__(256) void k_nodelin0(
        const float* __restrict__ nf,
        const float* __restrict__ wa, const float* __restrict__ ba,
        const float* __restrict__ wb, const float* __restrict__ bb,
        const float* __restrict__ wd, const float* __restrict__ bd,
        const float* __restrict__ we, const float* __restrict__ be,
        float* __restrict__ lin0, unsigned short* __restrict__ linB,
        unsigned short* __restrict__ linD, unsigned short* __restrict__ linE) {
    int idx = blockIdx.x * 256 + threadIdx.x;
    int n = idx >> 7, c = idx & 127;
    float x0 = nf[n * 2], x1 = nf[n * 2 + 1];
    lin0[idx] = fmaf(x0, wa[c], fmaf(x1, wa[128 + c], ba[c]));
    linB[idx] = f2b(fmaf(x0, wb[c], fmaf(x1, wb[128 + c], bb[c])));
    linD[idx] = f2b(fmaf(x0, wd[c], fmaf(x1, wd[128 + c], bd[c])));
    linE[idx] = f2b(fmaf(x0, we[c], fmaf(x1, we[128 + c], be[c])));
}

// ------- layer 0: edge output, CSR-ordered ebuf; 16 thr/edge, u16x8 I/O ---
__global__ __launch_bounds__(256) void k_edge0(
        const float* __restrict__ efseq,
        const float* __restrict__ cw, const float* __restrict__ cb,
        const int* __restrict__ srcseq, const int* __restrict__ dstseq,
        const unsigned short* __restrict__ linD, const unsigned short* __restrict__ linE,
        const float* __restrict__ g, const float* __restrict__ bt,
        unsigned short* __restrict__ ebuf) {
    const int tid = threadIdx.x;
    const int pos = blockIdx.x * 16 + (tid >> 4);
    const int c0 = (tid & 15) * 8;
    const int s = srcseq[pos], d = dstseq[pos];
    const float ev = efseq[pos];
    const u16x8 Dh = *(const u16x8*)(linD + (size_t)s * H + c0);
    const u16x8 Eh = *(const u16x8*)(linE + (size_t)d * H + c0);
    u16x8 o;
#pragma unroll
    for (int j = 0; j < 8; ++j) {
        float e2 = fmaf(ev, cw[c0 + j], cb[c0 + j]) + b2f(Dh[j]) + b2f(Eh[j]);
        o[j] = f2b(lrelu(eluf(fmaf(g[c0 + j], e2 * BN_S, bt[c0 + j]))));
    }
    *(u16x8*)(ebuf + (size_t)pos * H + c0) = o;
}

// ------- layer 0: fused aggregation + node update (pull, sequential) ------
__global__ __launch_bounds__(256) void k_agg0(
        const int* __restrict__ off, const int* __restrict__ deg,
        const int* __restrict__ srcseq, const float* __restrict__ efseq,
        const float* __restrict__ cw, const float* __restrict__ cb,
        const float* __restrict__ lin0, const unsigned short* __restrict__ linB,
        const unsigned short* __restrict__ linD, const unsigned short* __restrict__ linE,
        const float* __restrict__ g, const float* __restrict__ bt,
        float* __restrict__ hout, unsigned short* __restrict__ hbout) {
    const int tid = threadIdx.x;
    const int n = blockIdx.x * 2 + (tid >> 7);
    const int c = tid & 127;
    const int base = off[n], dg = deg[n];
    float num = 0.f, den = 0.f;
    const float Ehn = b2f(linE[(size_t)n * H + c]);
    const float cwc = cw[c], cbc = cb[c];
    int i = 0;
    for (; i + 4 <= dg; i += 4) {
        int s0 = srcseq[base + i],     s1 = srcseq[base + i + 1];
        int s2 = srcseq[base + i + 2], s3 = srcseq[base + i + 3];
        float x0 = fmaf(efseq[base + i],     cwc, cbc) + b2f(linD[(size_t)s0 * H + c]) + Ehn;
        float x1 = fmaf(efseq[base + i + 1], cwc, cbc) + b2f(linD[(size_t)s1 * H + c]) + Ehn;
        float x2 = fmaf(efseq[base + i + 2], cwc, cbc) + b2f(linD[(size_t)s2 * H + c]) + Ehn;
        float x3 = fmaf(efseq[base + i + 3], cwc, cbc) + b2f(linD[(size_t)s3 * H + c]) + Ehn;
        float g0 = sigf(x0), g1 = sigf(x1), g2 = sigf(x2), g3 = sigf(x3);
        num = fmaf(g0, b2f(linB[(size_t)s0 * H + c]), num); den += g0;
        num = fmaf(g1, b2f(linB[(size_t)s1 * H + c]), num); den += g1;
        num = fmaf(g2, b2f(linB[(size_t)s2 * H + c]), num); den += g2;
        num = fmaf(g3, b2f(linB[(size_t)s3 * H + c]), num); den += g3;
    }
    for (; i < dg; ++i) {
        int sa = srcseq[base + i];
        float xa = fmaf(efseq[base + i], cwc, cbc) + b2f(linD[(size_t)sa * H + c]) + Ehn;
        float ga = sigf(xa);
        num = fmaf(ga, b2f(linB[(size_t)sa * H + c]), num); den += ga;
    }
    float h2 = lin0[(size_t)n * H + c] + num / (den + 1e-6f);
    h2 = fmaf(g[c], h2 * BN_S, bt[c]);
    h2 = eluf(h2);
    float r = lrelu(h2);
    hout[(size_t)n * H + c] = r;
    hbout[(size_t)n * H + c] = f2b(r);
}

// ------- layers 1-2: fused aggregation + node update (pull e2seq) ---------
__global__ __launch_bounds__(256) void k_agg(
        const int* __restrict__ off, const int* __restrict__ deg,
        const int* __restrict__ srcseq,
        const unsigned short* __restrict__ e2seq,
        const float* __restrict__ lin0, const unsigned short* __restrict__ linB,
        const float* __restrict__ g, const float* __restrict__ bt,
        const float* __restrict__ hin, float* __restrict__ hout,
        unsigned short* __restrict__ hbout) {
    const int tid = threadIdx.x;
    const int n = blockIdx.x * 2 + (tid >> 7);
    const int c = tid & 127;
    const int base = off[n], dg = deg[n];
    float num = 0.f, den = 0.f;
    int i = 0;
    for (; i + 8 <= dg; i += 8) {
        int s[8];
        float x[8];
#pragma unroll
        for (int j = 0; j < 8; ++j) {
            s[j] = srcseq[base + i + j];
            x[j] = b2f(e2seq[(size_t)(base + i + j) * H + c]);
        }
        float gg[8];
#pragma unroll
        for (int j = 0; j < 8; ++j) gg[j] = sigf(x[j]);
#pragma unroll
        for (int j = 0; j < 8; ++j) {
            num = fmaf(gg[j], b2f(linB[(size_t)s[j] * H + c]), num);
            den += gg[j];
        }
    }
    for (; i < dg; ++i) {
        int sa = srcseq[base + i];
        float xa = b2f(e2seq[(size_t)(base + i) * H + c]);
        float ga = sigf(xa);
        num = fmaf(ga, b2f(linB[(size_t)sa * H + c]), num); den += ga;
    }
    float h2 = lin0[(size_t)n * H + c] + num / (den + 1e-6f);
    h2 = fmaf(g[c], h2 * BN_S, bt[c]);
    h2 = lrelu(h2);
    h2 += hin[(size_t)n * H + c];
    float r = lrelu(h2);
    hout[(size_t)n * H + c] = r;
    hbout[(size_t)n * H + c] = f2b(r);
}

// ---------------- MFMA node GEMM (bf16 h mirror in; mixed out) ------------
__global__ __launch_bounds__(256) void k_nodegemm(
        const unsigned short* __restrict__ hb,
        const unsigned short* __restrict__ wpack,
        const float* __restrict__ ba, const float* __restrict__ bb,
        const float* __restrict__ bd, const float* __restrict__ be,
        float* __restrict__ lin0, unsigned short* __restrict__ linB,
        unsigned short* __restrict__ linD, unsigned short* __restrict__ linE) {
    __shared__ __align__(16) unsigned short AT[64][136];
    const int tid = threadIdx.x;
    const int nbase = blockIdx.x * 64;
    const int which = blockIdx.y;
    const unsigned short* Wp = wpack + (size_t)which * 16384;
    const float* B = which == 0 ? ba : which == 1 ? bb : which == 2 ? bd : be;
#pragma unroll
    for (int rep = 0; rep < 4; ++rep) {
        int flat = (rep * 256 + tid) * 8;
        int r = flat >> 7, k0 = flat & 127;
        int n = nbase + r;
        u16x8 v = {};
        if (n < NN) v = *(const u16x8*)(hb + (size_t)n * H + k0);
        *(u16x8*)(&AT[r][k0]) = v;
    }
    __syncthreads();
    const int lane = tid & 63, wave = tid >> 6;
    const int lrow = lane & 15, quad = lane >> 4;
    f32x4 acc[8] = {};
#pragma unroll
    for (int kk = 0; kk < 4; ++kk) {
        bf16x8 af = *(const bf16x8*)(&AT[wave * 16 + lrow][kk * 32 + quad * 8]);
#pragma unroll
        for (int t = 0; t < 8; ++t) {
            bf16x8 bfv = *(const bf16x8*)(Wp + ((t * 4 + kk) * 64 + lane) * 8);
            acc[t] = __builtin_amdgcn_mfma_f32_16x16x32_bf16(af, bfv, acc[t], 0, 0, 0);
        }
    }
    unsigned short* linX = which == 1 ? linB : which == 2 ? linD : linE;
#pragma unroll
    for (int t = 0; t < 8; ++t) {
        int col = t * 16 + lrow;
        float bv = B[col];
#pragma unroll
        for (int reg = 0; reg < 4; ++reg) {
            int n = nbase + wave * 16 + quad * 4 + reg;
            if (n < NN) {
                float v = acc[t][reg] + bv;
                if (which == 0) lin0[(size_t)n * H + col] = v;
                else            linX[(size_t)n * H + col] = f2b(v);
            }
        }
    }
}

// ---- MLP node-chunk precompute: P1 = h@w1c0 + b1 ; P2 = h@w1c1 (bf16) ----
__global__ __launch_bounds__(256) void k_pgemm(
        const unsigned short* __restrict__ hb,
        const unsigned short* __restrict__ w1p,
        const float* __restrict__ b1,
        unsigned short* __restrict__ P) {
    __shared__ __align__(16) unsigned short AT[64][136];
    const int tid = threadIdx.x;
    const int nbase = blockIdx.x * 64;
    const int y = blockIdx.y;   // 0: P1 (+b1), 1: P2
    const unsigned short* Wp = w1p + (size_t)y * 16384;
#pragma unroll
    for (int rep = 0; rep < 4; ++rep) {
        int flat = (rep * 256 + tid) * 8;
        int r = flat >> 7, k0 = flat & 127;
        int n = nbase + r;
        u16x8 v = {};
        if (n < NN) v = *(const u16x8*)(hb + (size_t)n * H + k0);
        *(u16x8*)(&AT[r][k0]) = v;
    }
    __syncthreads();
    const int lane = tid & 63, wave = tid >> 6;
    const int lrow = lane & 15, quad = lane >> 4;
    f32x4 acc[8] = {};
#pragma unroll
    for (int kk = 0; kk < 4; ++kk) {
        bf16x8 af = *(const bf16x8*)(&AT[wave * 16 + lrow][kk * 32 + quad * 8]);
#pragma unroll
        for (int t = 0; t < 8; ++t) {
            bf16x8 bfv = *(const bf16x8*)(Wp + ((t * 4 + kk) * 64 + lane) * 8);
            acc[t] = __builtin_amdgcn_mfma_f32_16x16x32_bf16(af, bfv, acc[t], 0, 0, 0);
        }
    }
#pragma unroll
    for (int t = 0; t < 8; ++t) {
        int col = t * 16 + lrow;
        float bv = (y == 0) ? b1[col] : 0.f;
#pragma unroll
        for (int reg = 0; reg < 4; ++reg) {
            int n = nbase + wave * 16 + quad * 4 + reg;
            if (n < NN)
                P[(size_t)y * NH + (size_t)n * H + col] = f2b(acc[t][reg] + bv);
        }
    }
}

// ---- MFMA edge kernel (layers 1-2): round-11 structure, NO atomics -------
// 17.4 KB LDS -> 9 blocks/CU (occupancy > issue-count; rounds 5/12/13).
__global__ __launch_bounds__(256) void k_edgegemm(
        unsigned short* __restrict__ ebuf,
        unsigned short* __restrict__ e2seq,
        const unsigned short* __restrict__ Wp,
        const float* __restrict__ cb,
        const int* __restrict__ srcseq, const int* __restrict__ dstseq,
        const unsigned short* __restrict__ linD,
        const unsigned short* __restrict__ linE,
        const float* __restrict__ g, const float* __restrict__ bt) {
    __shared__ __align__(16) unsigned short AT[64][136];
    const int tid = threadIdx.x;
    const int ebase = blockIdx.x * 64;
#pragma unroll
    for (int rep = 0; rep < 4; ++rep) {
        int flat = (rep * 256 + tid) * 8;
        int r = flat >> 7, k0 = flat & 127;
        *(u16x8*)(&AT[r][k0]) = *(const u16x8*)(ebuf + (size_t)(ebase + r) * H + k0);
    }
    __syncthreads();
    const int lane = tid & 63, wave = tid >> 6;
    const int lrow = lane & 15, quad = lane >> 4;
    f32x4 acc[8] = {};
#pragma unroll
    for (int kk = 0; kk < 4; ++kk) {
        bf16x8 af = *(const bf16x8*)(&AT[wave * 16 + lrow][kk * 32 + quad * 8]);
#pragma unroll
        for (int t = 0; t < 8; ++t) {
            bf16x8 bfv = *(const bf16x8*)(Wp + ((t * 4 + kk) * 64 + lane) * 8);
            acc[t] = __builtin_amdgcn_mfma_f32_16x16x32_bf16(af, bfv, acc[t], 0, 0, 0);
        }
    }
    const int rr0 = wave * 16 + quad * 4;
    int sv[4], dv[4];
#pragma unroll
    for (int reg = 0; reg < 4; ++reg) {
        sv[reg] = srcseq[ebase + rr0 + reg];
        dv[reg] = dstseq[ebase + rr0 + reg];
    }
    unsigned short e2s[32];
#pragma unroll
    for (int t = 0; t < 8; ++t) {
        int col = t * 16 + lrow;
        float cbv = cb[col], gv = g[col], btv = bt[col];
#pragma unroll
        for (int reg = 0; reg < 4; ++reg) {
            float Dh = b2f(linD[(size_t)sv[reg] * H + col]);
            float Eh = b2f(linE[(size_t)dv[reg] * H + col]);
            float e2 = acc[t][reg] + cbv + Dh + Eh;
            e2s[t * 4 + reg] = f2b(e2);
            float tt = lrelu(fmaf(gv, e2 * BN_S, btv));
            float ein = b2f(AT[rr0 + reg][col]);       // residual from stage
            AT[rr0 + reg][col] = f2b(lrelu(tt + ein)); // in-place (owner lane)
        }
    }
    __syncthreads();
#pragma unroll
    for (int rep = 0; rep < 4; ++rep) {   // coalesced ebuf store
        int flat = (rep * 256 + tid) * 8;
        int r = flat >> 7, k0 = flat & 127;
        *(u16x8*)(ebuf + (size_t)(ebase + r) * H + k0) = *(const u16x8*)(&AT[r][k0]);
    }
    __syncthreads();
#pragma unroll
    for (int t = 0; t < 8; ++t)           // restage e2 into AT
#pragma unroll
        for (int reg = 0; reg < 4; ++reg)
            AT[rr0 + reg][t * 16 + lrow] = e2s[t * 4 + reg];
    __syncthreads();
#pragma unroll
    for (int rep = 0; rep < 4; ++rep) {   // coalesced e2seq store
        int flat = (rep * 256 + tid) * 8;
        int r = flat >> 7, k0 = flat & 127;
        *(u16x8*)(e2seq + (size_t)(ebase + r) * H + k0) = *(const u16x8*)(&AT[r][k0]);
    }
}

// ---------------- MLP edge kernel (round-11 version) ----------------------
__global__ __launch_bounds__(256) void k_mlp2(
        const unsigned short* __restrict__ ebuf,   // CSR order
        const unsigned short* __restrict__ P,      // P1 | P2 (bf16)
        const int* __restrict__ csr,
        const int* __restrict__ srcseq, const int* __restrict__ dstseq,
        const unsigned short* __restrict__ w1p2,   // w1 chunk2 pack
        const float* __restrict__ w2, const float* __restrict__ b2,
        float* __restrict__ out) {
    __shared__ __align__(16) unsigned short AT[64][136];
    const int tid = threadIdx.x;
    const int ebase = blockIdx.x * 64;
#pragma unroll
    for (int rep = 0; rep < 4; ++rep) {
        int flat = (rep * 256 + tid) * 8;
        int r = flat >> 7, k0 = flat & 127;
        *(u16x8*)(&AT[r][k0]) = *(const u16x8*)(ebuf + (size_t)(ebase + r) * H + k0);
    }
    __syncthreads();
    const int lane = tid & 63, wave = tid >> 6;
    const int lrow = lane & 15, quad = lane >> 4;
    f32x4 acc[8] = {};
#pragma unroll
    for (int kk = 0; kk < 4; ++kk) {
        bf16x8 af = *(const bf16x8*)(&AT[wave * 16 + lrow][kk * 32 + quad * 8]);
#pragma unroll
        for (int t = 0; t < 8; ++t) {
            bf16x8 bfv = *(const bf16x8*)(w1p2 + ((t * 4 + kk) * 64 + lane) * 8);
            acc[t] = __builtin_amdgcn_mfma_f32_16x16x32_bf16(af, bfv, acc[t], 0, 0, 0);
        }
    }
    const int e0 = ebase + wave * 16 + quad * 4;
    const float b20 = b2[0], b21 = b2[1];
#pragma unroll
    for (int reg = 0; reg < 4; ++reg) {
        const int e = e0 + reg;
        const int s = srcseq[e], d = dstseq[e];
        float p1v[8], p2v[8];
#pragma unroll
        for (int t = 0; t < 8; ++t) {   // preload all gathers -> deep ILP
            int col = t * 16 + lrow;
            p1v[t] = b2f(P[(size_t)s * H + col]);
            p2v[t] = b2f(P[(size_t)NH + (size_t)d * H + col]);
        }
        float p0 = 0.f, p1 = 0.f;
#pragma unroll
        for (int t = 0; t < 8; ++t) {
            int col = t * 16 + lrow;
            float hv = fmaxf(acc[t][reg] + p1v[t] + p2v[t], 0.f);  // b1 folded in P1
            p0 = fmaf(hv, w2[col * 2], p0);
            p1 = fmaf(hv, w2[col * 2 + 1], p1);
        }
#pragma unroll
        for (int off = 8; off; off >>= 1) {
            p0 += __shfl_xor(p0, off, 16);
            p1 += __shfl_xor(p1, off, 16);
        }
        if (lrow == 0) {
            int eid = csr[e];
            out[eid * 2]     = p0 + b20;
            out[eid * 2 + 1] = p1 + b21;
        }
    }
}

extern "C" void kernel_launch(void* const* d_in, const int* in_sizes, int n_in,
                              void* d_out, int out_size, void* d_ws, size_t ws_size,
                              hipStream_t stream) {
    const float* nf  = (const float*)d_in[0];
    const float* ef  = (const float*)d_in[1];
    const int*   src = (const int*)d_in[2];
    const int*   dst = (const int*)d_in[3];
    const float *a0w = (const float*)d_in[4],  *a0b = (const float*)d_in[5];
    const float *b0w = (const float*)d_in[6],  *b0b = (const float*)d_in[7];
    const float *c0w = (const float*)d_in[8],  *c0b = (const float*)d_in[9];
    const float *d0w = (const float*)d_in[10], *d0b = (const float*)d_in[11];
    const float *e0w = (const float*)d_in[12], *e0b = (const float*)d_in[13];
    const float *bnh0g = (const float*)d_in[14], *bnh0b = (const float*)d_in[15];
    const float *bne0g = (const float*)d_in[16], *bne0b = (const float*)d_in[17];
    const float *aLw = (const float*)d_in[18], *aLb = (const float*)d_in[19];
    const float *bLw = (const float*)d_in[20], *bLb = (const float*)d_in[21];
    const float *cLw = (const float*)d_in[22], *cLb = (const float*)d_in[23];
    const float *dLw = (const float*)d_in[24], *dLb = (const float*)d_in[25];
    const float *eLw = (const float*)d_in[26], *eLb = (const float*)d_in[27];
    const float *bnhLg = (const float*)d_in[28], *bnhLb = (const float*)d_in[29];
    const float *bneLg = (const float*)d_in[30], *bneLb = (const float*)d_in[31];
    const float *w1 = (const float*)d_in[32], *b1 = (const float*)d_in[33];
    const float *w2 = (const float*)d_in[34], *b2 = (const float*)d_in[35];
    float* out = (float*)d_out;

    // ws layout (~226 MB; cap lesson from round 3 — known-good is 246 MB):
    char* ws = (char*)d_ws;
    unsigned short* ebuf  = (unsigned short*)ws;                      // 81.92 MB
    unsigned short* e2seq = ebuf + (size_t)NE * H;                    // 81.92 MB
    float* lin0 = (float*)(e2seq + (size_t)NE * H);                   // 10.24 MB
    unsigned short* linB = (unsigned short*)(lin0 + NH);              // 5.12 MB
    unsigned short* linD = linB + NH;                                 // 5.12 MB
    unsigned short* linE = linD + NH;                                 // 5.12 MB
    float* h0  = (float*)(linE + NH);                                 // 10.24 MB
    float* h1  = h0 + NH;                                             // 10.24 MB
    unsigned short* hb0 = (unsigned short*)(h1 + NH);                 // 5.12 MB
    unsigned short* hb1 = hb0 + NH;                                   // 5.12 MB
    int* deg    = (int*)(hb1 + NH);
    int* off    = deg + NN;
    int* cursor = off + NN;
    int* csr    = cursor + NN;
    int* srcseq = csr + NE;
    int* dstseq = srcseq + NE;
    float* efseq = (float*)(dstseq + NE);
    unsigned short* wpack = (unsigned short*)(efseq + NE);
    unsigned short* P = e2seq;   // alias: e2seq dead after last k_agg

    // pack weights (13 matrices of 128x128 -> MFMA B-frag order)
    PackPtrs pp;
    const size_t HH = (size_t)H * H;
    for (int l = 0; l < 2; ++l) {
        pp.w[l * 5 + 0] = aLw + l * HH;
        pp.w[l * 5 + 1] = bLw + l * HH;
        pp.w[l * 5 + 2] = dLw + l * HH;
        pp.w[l * 5 + 3] = eLw + l * HH;
        pp.w[l * 5 + 4] = cLw + l * HH;
    }
    pp.w[10] = w1; pp.w[11] = w1 + HH; pp.w[12] = w1 + 2 * HH;
    k_pack<<<104, 256, 0, stream>>>(pp, wpack);

    // CSR build (in-edges, grouped by dst) + sequential tables in one pass
    hipMemsetAsync(deg, 0, NN * sizeof(int), stream);
    k_deg<<<(NE + 255) / 256, 256, 0, stream>>>(dst, deg);
    k_scan<<<1, 256, 0, stream>>>(deg, off, cursor);
    k_fill<<<(NE + 255) / 256, 256, 0, stream>>>(src, dst, ef, cursor, csr,
                                                 srcseq, dstseq, efseq);

    // ---- layer 0 ----
    k_nodelin0<<<NN * H / 256, 256, 0, stream>>>(nf, a0w, a0b, b0w, b0b, d0w, d0b,
                                                 e0w, e0b, lin0, linB, linD, linE);
    k_edge0<<<NE / 16, 256, 0, stream>>>(efseq, c0w, c0b, srcseq, dstseq, linD, linE,
                                         bne0g, bne0b, ebuf);
    k_agg0<<<NN / 2, 256, 0, stream>>>(off, deg, srcseq, efseq, c0w, c0b,
                                       lin0, linB, linD, linE, bnh0g, bnh0b, h0, hb0);

    // ---- layers 1..2 ----
    for (int l = 0; l < 2; ++l) {
        const float* hin = (l == 0) ? h0 : h1;
        float* hout      = (l == 0) ? h1 : h0;
        const unsigned short* hbin = (l == 0) ? hb0 : hb1;
        unsigned short* hbout      = (l == 0) ? hb1 : hb0;
        k_nodegemm<<<dim3(313, 4), 256, 0, stream>>>(hbin,
            wpack + (size_t)l * 5 * 16384,
            aLb + l * H, bLb + l * H, dLb + l * H, eLb + l * H,
            lin0, linB, linD, linE);
        k_edgegemm<<<NE / 64, 256, 0, stream>>>(ebuf, e2seq,
                                                wpack + (size_t)(l * 5 + 4) * 16384,
                                                cLb + l * H, srcseq, dstseq,
                                                linD, linE,
                                                bneLg + l * H, bneLb + l * H);
        k_agg<<<NN / 2, 256, 0, stream>>>(off, deg, srcseq, e2seq,
                                          lin0, linB, bnhLg + l * H, bnhLb + l * H,
                                          hin, hout, hbout);
    }

    // ---- edge classifier MLP ---- (final h mirror is hb0; e2seq dead -> P)
    k_pgemm<<<dim3(313, 2), 256, 0, stream>>>(hb0, wpack + 10ull * 16384, b1, P);
    k_mlp2<<<NE / 64, 256, 0, stream>>>(ebuf, P, csr, srcseq, dstseq,
                                        wpack + 12ull * 16384, w2, b2, out);

    (void)in_sizes; (void)n_in; (void)out_size; (void)ws_size;
}

// Round 15
// 611.943 us; speedup vs baseline: 1.4058x; 1.4058x over previous
//
#include <hip/hip_runtime.h>
#include <hip/hip_bf16.h>
#include <math.h>

#define NN 20000
#define NE 320000
#define H 128
#define NH (NN * H)

typedef short bf16x8 __attribute__((ext_vector_type(8)));
typedef float f32x4 __attribute__((ext_vector_type(4)));
typedef unsigned short u16x8 __attribute__((ext_vector_type(8)));

__device__ __forceinline__ float lrelu(float x) { return x > 0.f ? x : 0.01f * x; }
__device__ __forceinline__ float eluf(float x)  { return x > 0.f ? x : expm1f(x); }
__device__ __forceinline__ float sigf(float x)  { return 1.f / (1.f + __expf(-x)); }
__device__ __forceinline__ unsigned short f2b(float x) {
    __hip_bfloat16 h = __float2bfloat16(x);
    return *reinterpret_cast<unsigned short*>(&h);
}
__device__ __forceinline__ float b2f(unsigned short u) {
    __hip_bfloat16 h = *reinterpret_cast<__hip_bfloat16*>(&u);
    return __bfloat162float(h);
}
#define BN_S 0.99999500003749973f  /* 1/sqrt(1+1e-5) */

// ---------------- weight pre-pack into MFMA B-fragment order --------------
struct PackPtrs { const float* w[13]; };
__global__ __launch_bounds__(256) void k_pack(PackPtrs p, unsigned short* __restrict__ dst) {
    int gid = blockIdx.x * 256 + threadIdx.x;   // 13 * 2048 threads
    int m = gid >> 11;
    int r = gid & 2047;
    int t = r >> 8, kk = (r >> 6) & 3, lane = r & 63;
    const float* W = p.w[m];
    int col = t * 16 + (lane & 15);
    int krow = kk * 32 + (lane >> 4) * 8;
    unsigned short* o = dst + (size_t)m * 16384 + (size_t)r * 8;
#pragma unroll
    for (int j = 0; j < 8; ++j) o[j] = f2b(W[(krow + j) * H + col]);
}

// ---------------- CSR build ------------------------------------------------
__global__ __launch_bounds__(256) void k_deg(const int* __restrict__ dst, int* __restrict__ deg) {
    int e = blockIdx.x * 256 + threadIdx.x;
    if (e < NE) atomicAdd(&deg[dst[e]], 1);
}

__global__ __launch_bounds__(256) void k_scan(const int* __restrict__ deg,
                                              int* __restrict__ off, int* __restrict__ cursor) {
    __shared__ int sums[256];
    const int t = threadIdx.x;
    const int per = (NN + 255) / 256;   // 79
    const int base = t * per;
    int s = 0;
    for (int i = 0; i < per; ++i) { int idx = base + i; if (idx < NN) s += deg[idx]; }
    sums[t] = s;
    __syncthreads();
    for (int d = 1; d < 256; d <<= 1) {
        int v = (t >= d) ? sums[t - d] : 0;
        __syncthreads();
        sums[t] += v;
        __syncthreads();
    }
    int run = (t == 0) ? 0 : sums[t - 1];
    for (int i = 0; i < per; ++i) {
        int idx = base + i;
        if (idx < NN) { off[idx] = run; cursor[idx] = run; run += deg[idx]; }
    }
}

// fill CSR + sequential tables in one pass (ran clean in r12-r14)
__global__ __launch_bounds__(256) void k_fill(
        const int* __restrict__ src, const int* __restrict__ dst,
        const float* __restrict__ ef,
        int* __restrict__ cursor, int* __restrict__ csr,
        int* __restrict__ srcseq, int* __restrict__ dstseq,
        float* __restrict__ efseq) {
    int e = blockIdx.x * 256 + threadIdx.x;
    if (e < NE) {
        int d = dst[e];
        int pos = atomicAdd(&cursor[d], 1);
        csr[pos]    = e;
        srcseq[pos] = src[e];
        dstseq[pos] = d;
        efseq[pos]  = ef[e];
    }
}

// ---------------- layer 0: node linears (din=2) ----------------
__global__ __launch_bounds__(256) void k_nodelin0(
        const float* __restrict__ nf,
        const float* __restrict__ wa, const float* __restrict__ ba,
        const float* __restrict__ wb, const float* __restrict__ bb,
        const float* __restrict__ wd, const float* __restrict__ bd,
        const float* __restrict__ we, const float* __restrict__ be,
        float* __restrict__ lin0, unsigned short* __restrict__ linB,
        unsigned short* __restrict__ linD, unsigned short* __restrict__ linE) {
    int idx = blockIdx.x * 256 + threadIdx.x;
    int n = idx >> 7, c = idx & 127;
    float x0 = nf[n * 2], x1 = nf[n * 2 + 1];
    lin0[idx] = fmaf(x0, wa[c], fmaf(x1, wa[128 + c], ba[c]));
    linB[idx] = f2b(fmaf(x0, wb[c], fmaf(x1, wb[128 + c], bb[c])));
    linD[idx] = f2b(fmaf(x0, wd[c], fmaf(x1, wd[128 + c], bd[c])));
    linE[idx] = f2b(fmaf(x0, we[c], fmaf(x1, we[128 + c], be[c])));
}

// ------- layer 0: edge output (round-11 32-thread/float4 form) ------------
__global__ __launch_bounds__(256) void k_edge0(
        const float* __restrict__ efseq,
        const float* __restrict__ cw, const float* __restrict__ cb,
        const int* __restrict__ srcseq, const int* __restrict__ dstseq,
        const unsigned short* __restrict__ linD, const unsigned short* __restrict__ linE,
        const float* __restrict__ g, const float* __restrict__ bt,
        unsigned short* __restrict__ ebuf) {
    const int tid = threadIdx.x;
    const int pos = blockIdx.x * 8 + (tid >> 5);
    const int c0 = (tid & 31) * 4;
    const int s = srcseq[pos], d = dstseq[pos];
    const float ev = efseq[pos];
    const float4 cw4 = *(const float4*)(cw + c0);
    const float4 cb4 = *(const float4*)(cb + c0);
    const ushort4 Dh = *(const ushort4*)(linD + (size_t)s * H + c0);
    const ushort4 Eh = *(const ushort4*)(linE + (size_t)d * H + c0);
    const float4 g4  = *(const float4*)(g + c0);
    const float4 bt4 = *(const float4*)(bt + c0);
    float e2[4] = { fmaf(ev, cw4.x, cb4.x) + b2f(Dh.x) + b2f(Eh.x),
                    fmaf(ev, cw4.y, cb4.y) + b2f(Dh.y) + b2f(Eh.y),
                    fmaf(ev, cw4.z, cb4.z) + b2f(Dh.z) + b2f(Eh.z),
                    fmaf(ev, cw4.w, cb4.w) + b2f(Dh.w) + b2f(Eh.w) };
    const float gg[4] = { g4.x, g4.y, g4.z, g4.w };
    const float bb[4] = { bt4.x, bt4.y, bt4.z, bt4.w };
    ushort4 u;
    u.x = f2b(lrelu(eluf(fmaf(gg[0], e2[0] * BN_S, bb[0]))));
    u.y = f2b(lrelu(eluf(fmaf(gg[1], e2[1] * BN_S, bb[1]))));
    u.z = f2b(lrelu(eluf(fmaf(gg[2], e2[2] * BN_S, bb[2]))));
    u.w = f2b(lrelu(eluf(fmaf(gg[3], e2[3] * BN_S, bb[3]))));
    *(ushort4*)(ebuf + (size_t)pos * H + c0) = u;
}

// ------- layer 0: fused aggregation + node update (pull, sequential) ------
__global__ __launch_bounds__(256) void k_agg0(
        const int* __restrict__ off, const int* __restrict__ deg,
        const int* __restrict__ srcseq, const float* __restrict__ efseq,
        const float* __restrict__ cw, const float* __restrict__ cb,
        const float* __restrict__ lin0, const unsigned short* __restrict__ linB,
        const unsigned short* __restrict__ linD, const unsigned short* __restrict__ linE,
        const float* __restrict__ g, const float* __restrict__ bt,
        float* __restrict__ hout, unsigned short* __restrict__ hbout) {
    const int tid = threadIdx.x;
    const int n = blockIdx.x * 2 + (tid >> 7);
    const int c = tid & 127;
    const int base = off[n], dg = deg[n];
    float num = 0.f, den = 0.f;
    const float Ehn = b2f(linE[(size_t)n * H + c]);
    const float cwc = cw[c], cbc = cb[c];
    int i = 0;
    for (; i + 4 <= dg; i += 4) {
        int s0 = srcseq[base + i],     s1 = srcseq[base + i + 1];
        int s2 = srcseq[base + i + 2], s3 = srcseq[base + i + 3];
        float x0 = fmaf(efseq[base + i],     cwc, cbc) + b2f(linD[(size_t)s0 * H + c]) + Ehn;
        float x1 = fmaf(efseq[base + i + 1], cwc, cbc) + b2f(linD[(size_t)s1 * H + c]) + Ehn;
        float x2 = fmaf(efseq[base + i + 2], cwc, cbc) + b2f(linD[(size_t)s2 * H + c]) + Ehn;
        float x3 = fmaf(efseq[base + i + 3], cwc, cbc) + b2f(linD[(size_t)s3 * H + c]) + Ehn;
        float g0 = sigf(x0), g1 = sigf(x1), g2 = sigf(x2), g3 = sigf(x3);
        num = fmaf(g0, b2f(linB[(size_t)s0 * H + c]), num); den += g0;
        num = fmaf(g1, b2f(linB[(size_t)s1 * H + c]), num); den += g1;
        num = fmaf(g2, b2f(linB[(size_t)s2 * H + c]), num); den += g2;
        num = fmaf(g3, b2f(linB[(size_t)s3 * H + c]), num); den += g3;
    }
    for (; i < dg; ++i) {
        int sa = srcseq[base + i];
        float xa = fmaf(efseq[base + i], cwc, cbc) + b2f(linD[(size_t)sa * H + c]) + Ehn;
        float ga = sigf(xa);
        num = fmaf(ga, b2f(linB[(size_t)sa * H + c]), num); den += ga;
    }
    float h2 = lin0[(size_t)n * H + c] + num / (den + 1e-6f);
    h2 = fmaf(g[c], h2 * BN_S, bt[c]);
    h2 = eluf(h2);
    float r = lrelu(h2);
    hout[(size_t)n * H + c] = r;
    hbout[(size_t)n * H + c] = f2b(r);
}

// ------- layers 1-2: fused aggregation + node update (pull e2seq) ---------
__global__ __launch_bounds__(256) void k_agg(
        const int* __restrict__ off, const int* __restrict__ deg,
        const int* __restrict__ srcseq,
        const unsigned short* __restrict__ e2seq,
        const float* __restrict__ lin0, const unsigned short* __restrict__ linB,
        const float* __restrict__ g, const float* __restrict__ bt,
        const float* __restrict__ hin, float* __restrict__ hout,
        unsigned short* __restrict__ hbout) {
    const int tid = threadIdx.x;
    const int n = blockIdx.x * 2 + (tid >> 7);
    const int c = tid & 127;
    const int base = off[n], dg = deg[n];
    float num = 0.f, den = 0.f;
    int i = 0;
    for (; i + 8 <= dg; i += 8) {
        int s[8];
        float x[8];
#pragma unroll
        for (int j = 0; j < 8; ++j) {
            s[j] = srcseq[base + i + j];
            x[j] = b2f(e2seq[(size_t)(base + i + j) * H + c]);
        }
        float gg[8];
#pragma unroll
        for (int j = 0; j < 8; ++j) gg[j] = sigf(x[j]);
#pragma unroll
        for (int j = 0; j < 8; ++j) {
            num = fmaf(gg[j], b2f(linB[(size_t)s[j] * H + c]), num);
            den += gg[j];
        }
    }
    for (; i < dg; ++i) {
        int sa = srcseq[base + i];
        float xa = b2f(e2seq[(size_t)(base + i) * H + c]);
        float ga = sigf(xa);
        num = fmaf(ga, b2f(linB[(size_t)sa * H + c]), num); den += ga;
    }
    float h2 = lin0[(size_t)n * H + c] + num / (den + 1e-6f);
    h2 = fmaf(g[c], h2 * BN_S, bt[c]);
    h2 = lrelu(h2);
    h2 += hin[(size_t)n * H + c];
    float r = lrelu(h2);
    hout[(size_t)n * H + c] = r;
    hbout[(size_t)n * H + c] = f2b(r);
}

// ---------------- MFMA node GEMM (bf16 h mirror in; mixed out) ------------
__global__ __launch_bounds__(256) void k_nodegemm(
        const unsigned short* __restrict__ hb,
        const unsigned short* __restrict__ wpack,
        const float* __restrict__ ba, const float* __restrict__ bb,
        const float* __restrict__ bd, const float* __restrict__ be,
        float* __restrict__ lin0, unsigned short* __restrict__ linB,
        unsigned short* __restrict__ linD, unsigned short* __restrict__ linE) {
    __shared__ __align__(16) unsigned short AT[64][136];
    const int tid = threadIdx.x;
    const int nbase = blockIdx.x * 64;
    const int which = blockIdx.y;
    const unsigned short* Wp = wpack + (size_t)which * 16384;
    const float* B = which == 0 ? ba : which == 1 ? bb : which == 2 ? bd : be;
#pragma unroll
    for (int rep = 0; rep < 4; ++rep) {
        int flat = (rep * 256 + tid) * 8;
        int r = flat >> 7, k0 = flat & 127;
        int n = nbase + r;
        u16x8 v = {};
        if (n < NN) v = *(const u16x8*)(hb + (size_t)n * H + k0);
        *(u16x8*)(&AT[r][k0]) = v;
    }
    __syncthreads();
    const int lane = tid & 63, wave = tid >> 6;
    const int lrow = lane & 15, quad = lane >> 4;
    f32x4 acc[8] = {};
#pragma unroll
    for (int kk = 0; kk < 4; ++kk) {
        bf16x8 af = *(const bf16x8*)(&AT[wave * 16 + lrow][kk * 32 + quad * 8]);
#pragma unroll
        for (int t = 0; t < 8; ++t) {
            bf16x8 bfv = *(const bf16x8*)(Wp + ((t * 4 + kk) * 64 + lane) * 8);
            acc[t] = __builtin_amdgcn_mfma_f32_16x16x32_bf16(af, bfv, acc[t], 0, 0, 0);
        }
    }
    unsigned short* linX = which == 1 ? linB : which == 2 ? linD : linE;
#pragma unroll
    for (int t = 0; t < 8; ++t) {
        int col = t * 16 + lrow;
        float bv = B[col];
#pragma unroll
        for (int reg = 0; reg < 4; ++reg) {
            int n = nbase + wave * 16 + quad * 4 + reg;
            if (n < NN) {
                float v = acc[t][reg] + bv;
                if (which == 0) lin0[(size_t)n * H + col] = v;
                else            linX[(size_t)n * H + col] = f2b(v);
            }
        }
    }
}

// ---- MLP node-chunk precompute: P1 = h@w1c0 + b1 ; P2 = h@w1c1 (bf16) ----
__global__ __launch_bounds__(256) void k_pgemm(
        const unsigned short* __restrict__ hb,
        const unsigned short* __restrict__ w1p,
        const float* __restrict__ b1,
        unsigned short* __restrict__ P) {
    __shared__ __align__(16) unsigned short AT[64][136];
    const int tid = threadIdx.x;
    const int nbase = blockIdx.x * 64;
    const int y = blockIdx.y;   // 0: P1 (+b1), 1: P2
    const unsigned short* Wp = w1p + (size_t)y * 16384;
#pragma unroll
    for (int rep = 0; rep < 4; ++rep) {
        int flat = (rep * 256 + tid) * 8;
        int r = flat >> 7, k0 = flat & 127;
        int n = nbase + r;
        u16x8 v = {};
        if (n < NN) v = *(const u16x8*)(hb + (size_t)n * H + k0);
        *(u16x8*)(&AT[r][k0]) = v;
    }
    __syncthreads();
    const int lane = tid & 63, wave = tid >> 6;
    const int lrow = lane & 15, quad = lane >> 4;
    f32x4 acc[8] = {};
#pragma unroll
    for (int kk = 0; kk < 4; ++kk) {
        bf16x8 af = *(const bf16x8*)(&AT[wave * 16 + lrow][kk * 32 + quad * 8]);
#pragma unroll
        for (int t = 0; t < 8; ++t) {
            bf16x8 bfv = *(const bf16x8*)(Wp + ((t * 4 + kk) * 64 + lane) * 8);
            acc[t] = __builtin_amdgcn_mfma_f32_16x16x32_bf16(af, bfv, acc[t], 0, 0, 0);
        }
    }
#pragma unroll
    for (int t = 0; t < 8; ++t) {
        int col = t * 16 + lrow;
        float bv = (y == 0) ? b1[col] : 0.f;
#pragma unroll
        for (int reg = 0; reg < 4; ++reg) {
            int n = nbase + wave * 16 + quad * 4 + reg;
            if (n < NN)
                P[(size_t)y * NH + (size_t)n * H + col] = f2b(acc[t][reg] + bv);
        }
    }
}

// ---- MFMA edge kernel (layers 1-2): round-11 structure, NO atomics -------
// 17.4 KB LDS -> 9 blocks/CU (occupancy > issue-count; rounds 5/12/13).
__global__ __launch_bounds__(256) void k_edgegemm(
        unsigned short* __restrict__ ebuf,
        unsigned short* __restrict__ e2seq,
        const unsigned short* __restrict__ Wp,
        const float* __restrict__ cb,
        const int* __restrict__ srcseq, const int* __restrict__ dstseq,
        const unsigned short* __restrict__ linD,
        const unsigned short* __restrict__ linE,
        const float* __restrict__ g, const float* __restrict__ bt) {
    __shared__ __align__(16) unsigned short AT[64][136];
    const int tid = threadIdx.x;
    const int ebase = blockIdx.x * 64;
#pragma unroll
    for (int rep = 0; rep < 4; ++rep) {
        int flat = (rep * 256 + tid) * 8;
        int r = flat >> 7, k0 = flat & 127;
        *(u16x8*)(&AT[r][k0]) = *(const u16x8*)(ebuf + (size_t)(ebase + r) * H + k0);
    }
    __syncthreads();
    const int lane = tid & 63, wave = tid >> 6;
    const int lrow = lane & 15, quad = lane >> 4;
    f32x4 acc[8] = {};
#pragma unroll
    for (int kk = 0; kk < 4; ++kk) {
        bf16x8 af = *(const bf16x8*)(&AT[wave * 16 + lrow][kk * 32 + quad * 8]);
#pragma unroll
        for (int t = 0; t < 8; ++t) {
            bf16x8 bfv = *(const bf16x8*)(Wp + ((t * 4 + kk) * 64 + lane) * 8);
            acc[t] = __builtin_amdgcn_mfma_f32_16x16x32_bf16(af, bfv, acc[t], 0, 0, 0);
        }
    }
    const int rr0 = wave * 16 + quad * 4;
    int sv[4], dv[4];
#pragma unroll
    for (int reg = 0; reg < 4; ++reg) {
        sv[reg] = srcseq[ebase + rr0 + reg];
        dv[reg] = dstseq[ebase + rr0 + reg];
    }
    unsigned short e2s[32];
#pragma unroll
    for (int t = 0; t < 8; ++t) {
        int col = t * 16 + lrow;
        float cbv = cb[col], gv = g[col], btv = bt[col];
#pragma unroll
        for (int reg = 0; reg < 4; ++reg) {
            float Dh = b2f(linD[(size_t)sv[reg] * H + col]);
            float Eh = b2f(linE[(size_t)dv[reg] * H + col]);
            float e2 = acc[t][reg] + cbv + Dh + Eh;
            e2s[t * 4 + reg] = f2b(e2);
            float tt = lrelu(fmaf(gv, e2 * BN_S, btv));
            float ein = b2f(AT[rr0 + reg][col]);       // residual from stage
            AT[rr0 + reg][col] = f2b(lrelu(tt + ein)); // in-place (owner lane)
        }
    }
    __syncthreads();
#pragma unroll
    for (int rep = 0; rep < 4; ++rep) {   // coalesced ebuf store
        int flat = (rep * 256 + tid) * 8;
        int r = flat >> 7, k0 = flat & 127;
        *(u16x8*)(ebuf + (size_t)(ebase + r) * H + k0) = *(const u16x8*)(&AT[r][k0]);
    }
    __syncthreads();
#pragma unroll
    for (int t = 0; t < 8; ++t)           // restage e2 into AT
#pragma unroll
        for (int reg = 0; reg < 4; ++reg)
            AT[rr0 + reg][t * 16 + lrow] = e2s[t * 4 + reg];
    __syncthreads();
#pragma unroll
    for (int rep = 0; rep < 4; ++rep) {   // coalesced e2seq store
        int flat = (rep * 256 + tid) * 8;
        int r = flat >> 7, k0 = flat & 127;
        *(u16x8*)(e2seq + (size_t)(ebase + r) * H + k0) = *(const u16x8*)(&AT[r][k0]);
    }
}

// ---------------- MLP edge kernel (round-11 version) ----------------------
__global__ __launch_bounds__(256) void k_mlp2(
        const unsigned short* __restrict__ ebuf,   // CSR order
        const unsigned short* __restrict__ P,      // P1 | P2 (bf16)
        const int* __restrict__ csr,
        const int* __restrict__ srcseq, const int* __restrict__ dstseq,
        const unsigned short* __restrict__ w1p2,   // w1 chunk2 pack
        const float* __restrict__ w2, const float* __restrict__ b2,
        float* __restrict__ out) {
    __shared__ __align__(16) unsigned short AT[64][136];
    const int tid = threadIdx.x;
    const int ebase = blockIdx.x * 64;
#pragma unroll
    for (int rep = 0; rep < 4; ++rep) {
        int flat = (rep * 256 + tid) * 8;
        int r = flat >> 7, k0 = flat & 127;
        *(u16x8*)(&AT[r][k0]) = *(const u16x8*)(ebuf + (size_t)(ebase + r) * H + k0);
    }
    __syncthreads();
    const int lane = tid & 63, wave = tid >> 6;
    const int lrow = lane & 15, quad = lane >> 4;
    f32x4 acc[8] = {};
#pragma unroll
    for (int kk = 0; kk < 4; ++kk) {
        bf16x8 af = *(const bf16x8*)(&AT[wave * 16 + lrow][kk * 32 + quad * 8]);
#pragma unroll
        for (int t = 0; t < 8; ++t) {
            bf16x8 bfv = *(const bf16x8*)(w1p2 + ((t * 4 + kk) * 64 + lane) * 8);
            acc[t] = __builtin_amdgcn_mfma_f32_16x16x32_bf16(af, bfv, acc[t], 0, 0, 0);
        }
    }
    const int e0 = ebase + wave * 16 + quad * 4;
    const float b20 = b2[0], b21 = b2[1];
#pragma unroll
    for (int reg = 0; reg < 4; ++reg) {
        const int e = e0 + reg;
        const int s = srcseq[e], d = dstseq[e];
        float p1v[8], p2v[8];
#pragma unroll
        for (int t = 0; t < 8; ++t) {   // preload all gathers -> deep ILP
            int col = t * 16 + lrow;
            p1v[t] = b2f(P[(size_t)s * H + col]);
            p2v[t] = b2f(P[(size_t)NH + (size_t)d * H + col]);
        }
        float p0 = 0.f, p1 = 0.f;
#pragma unroll
        for (int t = 0; t < 8; ++t) {
            int col = t * 16 + lrow;
            float hv = fmaxf(acc[t][reg] + p1v[t] + p2v[t], 0.f);  // b1 folded in P1
            p0 = fmaf(hv, w2[col * 2], p0);
            p1 = fmaf(hv, w2[col * 2 + 1], p1);
        }
#pragma unroll
        for (int off = 8; off; off >>= 1) {
            p0 += __shfl_xor(p0, off, 16);
            p1 += __shfl_xor(p1, off, 16);
        }
        if (lrow == 0) {
            int eid = csr[e];
            out[eid * 2]     = p0 + b20;
            out[eid * 2 + 1] = p1 + b21;
        }
    }
}

extern "C" void kernel_launch(void* const* d_in, const int* in_sizes, int n_in,
                              void* d_out, int out_size, void* d_ws, size_t ws_size,
                              hipStream_t stream) {
    const float* nf  = (const float*)d_in[0];
    const float* ef  = (const float*)d_in[1];
    const int*   src = (const int*)d_in[2];
    const int*   dst = (const int*)d_in[3];
    const float *a0w = (const float*)d_in[4],  *a0b = (const float*)d_in[5];
    const float *b0w = (const float*)d_in[6],  *b0b = (const float*)d_in[7];
    const float *c0w = (const float*)d_in[8],  *c0b = (const float*)d_in[9];
    const float *d0w = (const float*)d_in[10], *d0b = (const float*)d_in[11];
    const float *e0w = (const float*)d_in[12], *e0b = (const float*)d_in[13];
    const float *bnh0g = (const float*)d_in[14], *bnh0b = (const float*)d_in[15];
    const float *bne0g = (const float*)d_in[16], *bne0b = (const float*)d_in[17];
    const float *aLw = (const float*)d_in[18], *aLb = (const float*)d_in[19];
    const float *bLw = (const float*)d_in[20], *bLb = (const float*)d_in[21];
    const float *cLw = (const float*)d_in[22], *cLb = (const float*)d_in[23];
    const float *dLw = (const float*)d_in[24], *dLb = (const float*)d_in[25];
    const float *eLw = (const float*)d_in[26], *eLb = (const float*)d_in[27];
    const float *bnhLg = (const float*)d_in[28], *bnhLb = (const float*)d_in[29];
    const float *bneLg = (const float*)d_in[30], *bneLb = (const float*)d_in[31];
    const float *w1 = (const float*)d_in[32], *b1 = (const float*)d_in[33];
    const float *w2 = (const float*)d_in[34], *b2 = (const float*)d_in[35];
    float* out = (float*)d_out;

    // ws layout (~226 MB; cap lesson from round 3 — known-good is 246 MB):
    char* ws = (char*)d_ws;
    unsigned short* ebuf  = (unsigned short*)ws;                      // 81.92 MB
    unsigned short* e2seq = ebuf + (size_t)NE * H;                    // 81.92 MB
    float* lin0 = (float*)(e2seq + (size_t)NE * H);                   // 10.24 MB
    unsigned short* linB = (unsigned short*)(lin0 + NH);              // 5.12 MB
    unsigned short* linD = linB + NH;                                 // 5.12 MB
    unsigned short* linE = linD + NH;                                 // 5.12 MB
    float* h0  = (float*)(linE + NH);                                 // 10.24 MB
    float* h1  = h0 + NH;                                             // 10.24 MB
    unsigned short* hb0 = (unsigned short*)(h1 + NH);                 // 5.12 MB
    unsigned short* hb1 = hb0 + NH;                                   // 5.12 MB
    int* deg    = (int*)(hb1 + NH);
    int* off    = deg + NN;
    int* cursor = off + NN;
    int* csr    = cursor + NN;
    int* srcseq = csr + NE;
    int* dstseq = srcseq + NE;
    float* efseq = (float*)(dstseq + NE);
    unsigned short* wpack = (unsigned short*)(efseq + NE);
    unsigned short* P = e2seq;   // alias: e2seq dead after last k_agg

    // pack weights (13 matrices of 128x128 -> MFMA B-frag order)
    PackPtrs pp;
    const size_t HH = (size_t)H * H;
    for (int l = 0; l < 2; ++l) {
        pp.w[l * 5 + 0] = aLw + l * HH;
        pp.w[l * 5 + 1] = bLw + l * HH;
        pp.w[l * 5 + 2] = dLw + l * HH;
        pp.w[l * 5 + 3] = eLw + l * HH;
        pp.w[l * 5 + 4] = cLw + l * HH;
    }
    pp.w[10] = w1; pp.w[11] = w1 + HH; pp.w[12] = w1 + 2 * HH;
    k_pack<<<104, 256, 0, stream>>>(pp, wpack);

    // CSR build (in-edges, grouped by dst) + sequential tables in one pass
    hipMemsetAsync(deg, 0, NN * sizeof(int), stream);
    k_deg<<<(NE + 255) / 256, 256, 0, stream>>>(dst, deg);
    k_scan<<<1, 256, 0, stream>>>(deg, off, cursor);
    k_fill<<<(NE + 255) / 256, 256, 0, stream>>>(src, dst, ef, cursor, csr,
                                                 srcseq, dstseq, efseq);

    // ---- layer 0 ----
    k_nodelin0<<<NN * H / 256, 256, 0, stream>>>(nf, a0w, a0b, b0w, b0b, d0w, d0b,
                                                 e0w, e0b, lin0, linB, linD, linE);
    k_edge0<<<NE / 8, 256, 0, stream>>>(efseq, c0w, c0b, srcseq, dstseq, linD, linE,
                                        bne0g, bne0b, ebuf);
    k_agg0<<<NN / 2, 256, 0, stream>>>(off, deg, srcseq, efseq, c0w, c0b,
                                       lin0, linB, linD, linE, bnh0g, bnh0b, h0, hb0);

    // ---- layers 1..2 ----
    for (int l = 0; l < 2; ++l) {
        const float* hin = (l == 0) ? h0 : h1;
        float* hout      = (l == 0) ? h1 : h0;
        const unsigned short* hbin = (l == 0) ? hb0 : hb1;
        unsigned short* hbout      = (l == 0) ? hb1 : hb0;
        k_nodegemm<<<dim3(313, 4), 256, 0, stream>>>(hbin,
            wpack + (size_t)l * 5 * 16384,
            aLb + l * H, bLb + l * H, dLb + l * H, eLb + l * H,
            lin0, linB, linD, linE);
        k_edgegemm<<<NE / 64, 256, 0, stream>>>(ebuf, e2seq,
                                                wpack + (size_t)(l * 5 + 4) * 16384,
                                                cLb + l * H, srcseq, dstseq,
                                                linD, linE,
                                                bneLg + l * H, bneLb + l * H);
        k_agg<<<NN / 2, 256, 0, stream>>>(off, deg, srcseq, e2seq,
                                          lin0, linB, bnhLg + l * H, bnhLb + l * H,
                                          hin, hout, hbout);
    }

    // ---- edge classifier MLP ---- (final h mirror is hb0; e2seq dead -> P)
    k_pgemm<<<dim3(313, 2), 256, 0, stream>>>(hb0, wpack + 10ull * 16384, b1, P);
    k_mlp2<<<NE / 64, 256, 0, stream>>>(ebuf, P, csr, srcseq, dstseq,
                                        wpack + 12ull * 16384, w2, b2, out);

    (void)in_sizes; (void)n_in; (void)out_size; (void)ws_size;
}